// Round 10
// baseline (196.086 us; speedup 1.0000x reference)
//
#include <hip/hip_runtime.h>

// Weighted BCE over (N=4, C=3, 128^3) fp32.
// Identity (t in {0,1} exactly): t*log(p)+(1-t)*log(1-p) = log(t ? p : 1-p);
// count(t!=0) = sum(t) (float-exact below 2^24).
//
// R9 post-mortem: nt loads + TLP -> partial ~55 us (3.6 TB/s read). VGPR
// path is stuck at ~2 loads/wave in flight (compiler load-sink, proven
// R3/R6). R10: the one untested combination -- NONTEMPORAL direct-to-LDS
// DMA pipeline (R7 apparatus, aux=2 = CPol.NT): guaranteed 8 KB/wave
// outstanding (96 KB/CU vs ~64 on the VGPR path) AND no L2-install churn.
// Wave-private triple buffer, no __syncthreads in stream loop, completion
// via s_waitcnt vmcnt(4).

#define THREADS 256
#define WAVES (THREADS / 64)
#define BLOCKS_PER_SLAB 128
#define NSLABS 12            // N*C
#define NCHAN 3
#define ENTRIES_PER_CHAN (4 * BLOCKS_PER_SLAB)   // 512

// staging geometry (per wave): stage = 2 KB input + 2 KB target = 4 instrs
#define STAGE_F4 128                   // float4 per array per stage
#define INSTR_PER_ARRAY 2              // 2 x (16 B x 64 lanes)
#define NSTAGE 8                       // per-wave chunk = 1024 float4 per array
#define NBUF 3                         // triple buffer
#define BUF_BYTES 4096
#define WAVE_LDS (NBUF * BUF_BYTES)    // 12 KB
#define BLOCK_LDS (WAVES * WAVE_LDS)   // 48 KB -> 3 blocks/CU

#define CPOL_NT 2                      // CPol bit1 = NT (gfx940+)

// s_waitcnt imm (gfx9 encoding): vmcnt[3:0], expcnt=7 [6:4], lgkmcnt=15 [11:8]
#define WAITVM(N) __builtin_amdgcn_s_waitcnt(0x0F70 | (N))

typedef __attribute__((address_space(1))) const void gvoid_t;
typedef __attribute__((address_space(3))) void lvoid_t;

__device__ __forceinline__ void stage_issue(
    const float4* __restrict__ gin, const float4* __restrict__ gtg,
    int f4idx, char* lbuf /*wave-uniform*/, int lane)
{
#pragma unroll
    for (int q = 0; q < INSTR_PER_ARRAY; ++q)
        __builtin_amdgcn_global_load_lds(
            (gvoid_t*)(gin + f4idx + q * 64 + lane),
            (lvoid_t*)(lbuf + q * 1024), 16, 0, CPOL_NT);
#pragma unroll
    for (int q = 0; q < INSTR_PER_ARRAY; ++q)
        __builtin_amdgcn_global_load_lds(
            (gvoid_t*)(gtg + f4idx + q * 64 + lane),
            (lvoid_t*)(lbuf + 2048 + q * 1024), 16, 0, CPOL_NT);
}

__device__ __forceinline__ void acc4(float4 p, float4 t, float& lsum, float& lcnt)
{
    float pp[4] = {p.x, p.y, p.z, p.w};
    float tt[4] = {t.x, t.y, t.z, t.w};
#pragma unroll
    for (int k = 0; k < 4; ++k) {
        bool  pos = (tt[k] != 0.0f);
        float x   = pos ? pp[k] : (1.0f - pp[k]);
        lsum += fmaxf(__logf(x), -100.0f);          // one v_log_f32
        lcnt += tt[k];
    }
}

__global__ __launch_bounds__(THREADS) void bce_partial(
    const float* __restrict__ input,
    const float* __restrict__ target,
    float* __restrict__ psum,    // [3*512]
    float* __restrict__ pcnt,    // [3*512]
    int S4)                       // float4 per slab (524288)
{
    __shared__ __align__(16) char smem[BLOCK_LDS];

    const int slab = blockIdx.x / BLOCKS_PER_SLAB;
    const int blk  = blockIdx.x % BLOCKS_PER_SLAB;
    const int c    = slab % NCHAN;              // block-uniform

    const int lane = threadIdx.x & 63;
    const int wv   = threadIdx.x >> 6;

    const float4* __restrict__ in4 = (const float4*)input  + (size_t)slab * S4;
    const float4* __restrict__ tg4 = (const float4*)target + (size_t)slab * S4;

    // per-wave contiguous chunk of 1024 float4 per array
    const int chunk = (blk * WAVES + wv) * (NSTAGE * STAGE_F4);
    char* wlds = smem + wv * WAVE_LDS;          // wave-private region

    // prologue: 2 stages in flight (8 vmem instrs, 8 KB)
    stage_issue(in4, tg4, chunk + 0 * STAGE_F4, wlds + 0 * BUF_BYTES, lane);
    stage_issue(in4, tg4, chunk + 1 * STAGE_F4, wlds + 1 * BUF_BYTES, lane);

    float lsum = 0.0f, lcnt = 0.0f;

#pragma unroll
    for (int j = 0; j < NSTAGE; ++j) {
        // stage j complete when <= 4 vmem ops outstanding (stage j+1's)
        if (j < NSTAGE - 1) WAITVM(4); else WAITVM(0);
        __builtin_amdgcn_sched_barrier(0);      // no ds_read hoisted above wait

        const float4* buf = (const float4*)(wlds + (j % NBUF) * BUF_BYTES);
#pragma unroll
        for (int q = 0; q < INSTR_PER_ARRAY; ++q) {
            float4 p = buf[q * 64 + lane];          // own staged data
            float4 t = buf[128 + q * 64 + lane];
            acc4(p, t, lsum, lcnt);
        }
        __builtin_amdgcn_sched_barrier(0);      // issue stays after reads

        if (j + 2 < NSTAGE)                      // buffer (j+2)%3 is idle
            stage_issue(in4, tg4, chunk + (j + 2) * STAGE_F4,
                        wlds + ((j + 2) % NBUF) * BUF_BYTES, lane);
    }

    // ---- block reduction (no atomics; plain stores to distinct addrs) ----
#pragma unroll
    for (int off = 32; off > 0; off >>= 1) {
        lsum += __shfl_down(lsum, off, 64);
        lcnt += __shfl_down(lcnt, off, 64);
    }

    __shared__ float wsum[WAVES];
    __shared__ float wcnt[WAVES];
    if (lane == 0) { wsum[wv] = lsum; wcnt[wv] = lcnt; }
    __syncthreads();
    if (threadIdx.x == 0) {
        float s = 0.0f, n = 0.0f;
#pragma unroll
        for (int w = 0; w < WAVES; ++w) { s += wsum[w]; n += wcnt[w]; }
        const int e = c * ENTRIES_PER_CHAN + (slab / NCHAN) * BLOCKS_PER_SLAB + blk;
        psum[e] = s;
        pcnt[e] = n;
    }
}

__global__ __launch_bounds__(THREADS) void bce_final(
    const float* __restrict__ psum,
    const float* __restrict__ pcnt,
    float* __restrict__ out,
    float per_chan_total)
{
    const int tid = (int)threadIdx.x;
    float s[NCHAN], n[NCHAN];
#pragma unroll
    for (int c = 0; c < NCHAN; ++c) {
        const int b = c * ENTRIES_PER_CHAN + tid;
        s[c] = psum[b] + psum[b + THREADS];
        n[c] = pcnt[b] + pcnt[b + THREADS];
    }
#pragma unroll
    for (int off = 32; off > 0; off >>= 1) {
#pragma unroll
        for (int c = 0; c < NCHAN; ++c) {
            s[c] += __shfl_down(s[c], off, 64);
            n[c] += __shfl_down(n[c], off, 64);
        }
    }
    __shared__ float ws[THREADS / 64][NCHAN], wn[THREADS / 64][NCHAN];
    const int lane = tid & 63, wave = tid >> 6;
    if (lane == 0) {
#pragma unroll
        for (int c = 0; c < NCHAN; ++c) { ws[wave][c] = s[c]; wn[wave][c] = n[c]; }
    }
    __syncthreads();
    if (tid == 0) {
        float acc = 0.0f;
#pragma unroll
        for (int c = 0; c < NCHAN; ++c) {
            float ssum = 0.0f, ncnt = 0.0f;
#pragma unroll
            for (int w = 0; w < THREADS / 64; ++w) { ssum += ws[w][c]; ncnt += wn[w][c]; }
            float w8  = (ncnt > 0.0f) ? (per_chan_total / fmaxf(ncnt, 1.0f)) : 1000.0f;
            float bce = -(ssum / per_chan_total);
            acc += w8 * bce;
        }
        out[0] = acc / (float)NCHAN;
    }
}

extern "C" void kernel_launch(void* const* d_in, const int* in_sizes, int n_in,
                              void* d_out, int out_size, void* d_ws, size_t ws_size,
                              hipStream_t stream)
{
    const float* input  = (const float*)d_in[0];
    const float* target = (const float*)d_in[1];
    float*       out    = (float*)d_out;

    const int nentry = NCHAN * ENTRIES_PER_CHAN;          // 1536
    float* psum = (float*)d_ws;
    float* pcnt = (float*)d_ws + nentry;

    const long long total = (long long)in_sizes[0];        // 25,165,824
    const int       S4    = (int)(total / (NSLABS * 4));    // 524,288
    const float     M     = (float)(total / NCHAN);         // 8,388,608

    bce_partial<<<NSLABS * BLOCKS_PER_SLAB, THREADS, 0, stream>>>(
        input, target, psum, pcnt, S4);
    bce_final<<<1, THREADS, 0, stream>>>(psum, pcnt, out, M);
}